// Round 5
// baseline (169.410 us; speedup 1.0000x reference)
//
#include <hip/hip_runtime.h>
#include <hip/hip_bf16.h>
#include <stdint.h>

// Problem constants
#define B_ 4
#define L_ 1024
#define D_ 768
#define H_ 12
#define HD_ 64
#define M_ 4096     // B*L
#define N3_ 2304    // 3*D

typedef float f32x4 __attribute__((ext_vector_type(4)));
typedef float f32x4v __attribute__((ext_vector_type(4)));
typedef short bf16x8 __attribute__((ext_vector_type(8)));
typedef unsigned short u16;
typedef u16 u16x8 __attribute__((ext_vector_type(8)));
typedef u16 u16x4 __attribute__((ext_vector_type(4)));
typedef uint32_t u32x2 __attribute__((ext_vector_type(2)));

#define AS3 __attribute__((address_space(3)))
#define AS1 __attribute__((address_space(1)))

__device__ __forceinline__ void gll16(const void* g, void* l) {
  __builtin_amdgcn_global_load_lds((const AS1 void*)g, (AS3 void*)l, 16, 0, 0);
}

// fp32 -> bf16 round-to-nearest-even (finite data)
__device__ __forceinline__ u16 f2bf(float f) {
  uint32_t u = __builtin_bit_cast(uint32_t, f);
  u += 0x7fffu + ((u >> 16) & 1u);
  return (u16)(u >> 16);
}

// ---------------- fused conversion kernel (3 tensors, fp32 -> bf16) ---------
__global__ void k_cvt3(const float* __restrict__ a, u16* __restrict__ ao, int na4,
                       const float* __restrict__ b, u16* __restrict__ bo, int nb4,
                       const float* __restrict__ c, u16* __restrict__ co, int nc4) {
  int i = blockIdx.x * 256 + threadIdx.x;
  const float* src;
  u16* dst;
  if (i < na4) {
    src = a; dst = ao;
  } else if (i < na4 + nb4) {
    src = b; dst = bo; i -= na4;
  } else if (i < na4 + nb4 + nc4) {
    src = c; dst = co; i -= na4 + nb4;
  } else {
    return;
  }
  f32x4v v = ((const f32x4v*)src)[i];
  u16x4 o;
  o.x = f2bf(v.x); o.y = f2bf(v.y); o.z = f2bf(v.z); o.w = f2bf(v.w);
  ((u16x4*)dst)[i] = o;
}

// ---------------- GEMM1: qkv = x @ w_in^T + b_in -> Q,K,V bf16 [B,H,L,64] ----
__global__ __launch_bounds__(256) void k_gemm_qkv(
    const u16* __restrict__ Xb, const u16* __restrict__ Wb,
    const float* __restrict__ b_in,
    u16* __restrict__ gQ, u16* __restrict__ gK, u16* __restrict__ gV) {
  __shared__ u16 As[128 * 64];
  __shared__ u16 Bs[128 * 64];
  const int tid = threadIdx.x;
  const int lane = tid & 63;
  const int w = tid >> 6;
  const int wm = (w >> 1) * 64;
  const int wn = (w & 1) * 64;
  const int lr = lane & 15;
  const int lg = lane >> 4;
  const int m0 = blockIdx.x * 128;
  const int n0 = blockIdx.y * 128;

  f32x4 acc[4][4];
#pragma unroll
  for (int i = 0; i < 4; ++i)
#pragma unroll
    for (int j = 0; j < 4; ++j) acc[i][j] = (f32x4){0.f, 0.f, 0.f, 0.f};

  for (int kt = 0; kt < 12; ++kt) {
    __syncthreads();
#pragma unroll
    for (int i = 0; i < 4; ++i) {
      int seg = i * 256 + tid;
      int row = seg >> 3;
      int sl = (seg & 7) ^ (row & 7);
      gll16(Xb + (size_t)(m0 + row) * 768 + kt * 64 + sl * 8, (char*)As + seg * 16);
      gll16(Wb + (size_t)(n0 + row) * 768 + kt * 64 + sl * 8, (char*)Bs + seg * 16);
    }
    __syncthreads();
#pragma unroll
    for (int kh = 0; kh < 2; ++kh) {
      bf16x8 af[4], bfr[4];
#pragma unroll
      for (int t = 0; t < 4; ++t) {
        int ra = wm + t * 16 + lr;
        af[t] = *(const bf16x8*)((const char*)As + ra * 128 +
                                 ((kh * 64 + lg * 16) ^ ((ra & 7) << 4)));
        int rb = wn + t * 16 + lr;
        bfr[t] = *(const bf16x8*)((const char*)Bs + rb * 128 +
                                  ((kh * 64 + lg * 16) ^ ((rb & 7) << 4)));
      }
#pragma unroll
      for (int mi = 0; mi < 4; ++mi)
#pragma unroll
        for (int ni = 0; ni < 4; ++ni)
          acc[mi][ni] = __builtin_amdgcn_mfma_f32_16x16x32_bf16(
              af[mi], bfr[ni], acc[mi][ni], 0, 0, 0);
    }
  }
  // epilogue: +b_in, scale q, scatter to [B,H,L,64] bf16
  const int sec = blockIdx.y / 6;  // 0=q,1=k,2=v
  u16* dst = sec == 0 ? gQ : (sec == 1 ? gK : gV);
  const float scale = sec == 0 ? 0.125f : 1.0f;
#pragma unroll
  for (int ni = 0; ni < 4; ++ni) {
    int e = n0 + wn + ni * 16 + lr;  // 0..2303
    float bias = b_in[e];
    int es = e - sec * 768;
    int h = es >> 6, d = es & 63;
#pragma unroll
    for (int mi = 0; mi < 4; ++mi) {
#pragma unroll
      for (int j = 0; j < 4; ++j) {
        int m = m0 + wm + mi * 16 + lg * 4 + j;
        int bb = m >> 10, lq = m & 1023;
        float vv = (acc[mi][ni][j] + bias) * scale;
        dst[(size_t)((bb * 12 + h) * 1024 + lq) * 64 + d] = f2bf(vv);
      }
    }
  }
}

// ---------------- V transpose: [B,H,L,64] -> [B,H,64,L] ---------------------
__global__ __launch_bounds__(256) void k_transpose(const u16* __restrict__ V,
                                                   u16* __restrict__ Vt) {
  __shared__ u16 t[64][66];
  const int tid = threadIdx.x;
  const int bh = blockIdx.x >> 4;
  const int kv0 = (blockIdx.x & 15) * 64;
  {
    int r = tid >> 2, c0 = (tid & 3) * 16;
    const u16* src = V + (size_t)(bh * 1024 + kv0 + r) * 64 + c0;
#pragma unroll
    for (int p = 0; p < 2; ++p) {
      u16x8 x = *(const u16x8*)(src + p * 8);
#pragma unroll
      for (int e = 0; e < 8; ++e) t[r][c0 + p * 8 + e] = x[e];
    }
  }
  __syncthreads();
  {
    int d = tid >> 2, k0 = (tid & 3) * 16;
    u16* dst = Vt + (size_t)(bh * 64 + d) * 1024 + kv0 + k0;
#pragma unroll
    for (int p = 0; p < 2; ++p) {
      u16x8 o;
#pragma unroll
      for (int e = 0; e < 8; ++e) o[e] = t[k0 + p * 8 + e][d];
      *(u16x8*)(dst + p * 8) = o;
    }
  }
}

// ---------------- fused flash attention (barrier-free) ----------------------
// Swapped QK^T (lane-local softmax). NO barriers: each wave free-runs its
// 16 q-rows x 16 kv-tiles with private register pipelines. K/V fragments
// loaded per-wave direct from L2 (XCD swizzle keeps them resident); K
// reloaded right after QK^T consumes it, V right after PV. Bias depth-2
// register prefetch. P bounced through per-wave LDS (lgkm only, no barrier).
__global__ __launch_bounds__(256, 3) void k_attn(
    const u16* __restrict__ gQ, const u16* __restrict__ gK,
    const u16* __restrict__ gVt, const float* __restrict__ gBias,
    u16* __restrict__ gO) {
  __shared__ f32x4 PlV[4][128];  // per-wave 2KB P bounce
  const int tid = threadIdx.x;
  const int lane = tid & 63;
  const int w = tid >> 6;
  const int lr = lane & 15;
  const int lg = lane >> 4;
  // XCD-bijective swizzle: 768 = 8 XCDs x 96; the 16 q-blocks sharing one
  // (b,h)'s K/V land on one XCD -> K/V stay L2-resident.
  const int lb = (blockIdx.x & 7) * 96 + (blockIdx.x >> 3);
  const int bh = lb >> 4;
  const int q0 = (lb & 15) * 64;
  const int qr = q0 + w * 16;  // wave's q-row base; lane's q-row = qr + lr

  const u16* kbase = gK + ((size_t)bh << 16);
  const u16* vbase = gVt + ((size_t)bh << 16);
  const float* bline = gBias + (size_t)(bh * 1024 + qr + lr) * 1024;

#define LOAD_KB(kv0)                                                           \
  do {                                                                         \
    _Pragma("unroll") for (int kh_ = 0; kh_ < 2; ++kh_)                        \
    _Pragma("unroll") for (int ni_ = 0; ni_ < 4; ++ni_)                        \
      kb[kh_][ni_] = *(const bf16x8*)(                                         \
          kbase + (size_t)((kv0) + ni_ * 16 + lr) * 64 + kh_ * 32 + lg * 8);   \
  } while (0)

#define LOAD_VB(kv0)                                                           \
  do {                                                                         \
    _Pragma("unroll") for (int kh_ = 0; kh_ < 2; ++kh_)                        \
    _Pragma("unroll") for (int dt_ = 0; dt_ < 4; ++dt_)                        \
      vb[kh_][dt_] = *(const bf16x8*)(                                         \
          vbase + (size_t)(dt_ * 16 + lr) * 1024 + (kv0) + kh_ * 32 + lg * 8); \
  } while (0)

#define BIAS_LOAD(dst, kv0)                                                    \
  do {                                                                         \
    _Pragma("unroll") for (int ni_ = 0; ni_ < 4; ++ni_)                        \
      dst[ni_] = *(const f32x4*)(bline + (kv0) + ni_ * 16 + lg * 4);           \
  } while (0)

  // Q as B-operand: rows q = qr+lr (pre-scaled by 1/8 in GEMM1)
  bf16x8 qa[2];
#pragma unroll
  for (int kh = 0; kh < 2; ++kh)
    qa[kh] = *(const bf16x8*)(gQ + (size_t)(bh * 1024 + qr + lr) * 64 + kh * 32 + lg * 8);

  f32x4 oacc[4];
#pragma unroll
  for (int dt = 0; dt < 4; ++dt) oacc[dt] = (f32x4){0.f, 0.f, 0.f, 0.f};
  float mrow = -1e30f, lrow = 0.f;

  char* plw = (char*)PlV[w];
  const int swz = (lr & 7) << 4;

  // prologue: K/V fragments for tile 0, bias tiles 0,1
  bf16x8 kb[2][4], vb[2][4];
  f32x4 bcur[4], bnext[4];
  LOAD_KB(0);
  LOAD_VB(0);
  BIAS_LOAD(bcur, 0);
  BIAS_LOAD(bnext, 64);

  for (int t = 0; t < 16; ++t) {
    // S^T = K Q^T : s[ni][j] = S[kv = ni*16+lg*4+j][q = qr+lr]
    f32x4 s[4];
#pragma unroll
    for (int ni = 0; ni < 4; ++ni) s[ni] = (f32x4){0.f, 0.f, 0.f, 0.f};
    __builtin_amdgcn_s_setprio(1);
#pragma unroll
    for (int kh = 0; kh < 2; ++kh)
#pragma unroll
      for (int ni = 0; ni < 4; ++ni)
        s[ni] = __builtin_amdgcn_mfma_f32_16x16x32_bf16(kb[kh][ni], qa[kh], s[ni], 0, 0, 0);
    __builtin_amdgcn_s_setprio(0);

    // prefetch next K tile (cover = softmax + PV)
    if (t < 15) LOAD_KB((t + 1) * 64);

    // + bias (depth-2 prefetched registers)
#pragma unroll
    for (int ni = 0; ni < 4; ++ni) s[ni] += bcur[ni];

    // issue bias loads for tile t+2
    f32x4 bnew[4];
    if (t < 14) BIAS_LOAD(bnew, (t + 2) * 64);

    // lane-local online softmax for q-row (qr+lr)
    float mx0 = fmaxf(fmaxf(s[0][0], s[0][1]), fmaxf(s[0][2], s[0][3]));
    float mx1 = fmaxf(fmaxf(s[1][0], s[1][1]), fmaxf(s[1][2], s[1][3]));
    float mx2 = fmaxf(fmaxf(s[2][0], s[2][1]), fmaxf(s[2][2], s[2][3]));
    float mx3 = fmaxf(fmaxf(s[3][0], s[3][1]), fmaxf(s[3][2], s[3][3]));
    float vmax = fmaxf(fmaxf(mx0, mx1), fmaxf(mx2, mx3));
    vmax = fmaxf(vmax, __shfl_xor(vmax, 16));
    vmax = fmaxf(vmax, __shfl_xor(vmax, 32));
    float mnew = fmaxf(mrow, vmax);
    float al = __expf(mrow - mnew);
    mrow = mnew;
#pragma unroll
    for (int ni = 0; ni < 4; ++ni)
#pragma unroll
      for (int j = 0; j < 4; ++j) s[ni][j] = __expf(s[ni][j] - mnew);
    float r0 = (s[0][0] + s[0][1]) + (s[0][2] + s[0][3]);
    float r1 = (s[1][0] + s[1][1]) + (s[1][2] + s[1][3]);
    float r2 = (s[2][0] + s[2][1]) + (s[2][2] + s[2][3]);
    float r3 = (s[3][0] + s[3][1]) + (s[3][2] + s[3][3]);
    float rs = (r0 + r1) + (r2 + r3);
    rs += __shfl_xor(rs, 16);
    rs += __shfl_xor(rs, 32);
    lrow = lrow * al + rs;

    // broadcast al from lane (lr = q) to the oacc owners (q = lg*4+j)
    f32x4 av;
#pragma unroll
    for (int j = 0; j < 4; ++j) av[j] = __shfl(al, (lane & 48) | (lg * 4 + j));
#pragma unroll
    for (int dt = 0; dt < 4; ++dt) oacc[dt] *= av;

    // P pack -> per-wave swizzled LDS (b64), read back as A-fragment, PV
#pragma unroll
    for (int ni = 0; ni < 4; ++ni) {
      uint32_t w0 = (uint32_t)f2bf(s[ni][0]) | ((uint32_t)f2bf(s[ni][1]) << 16);
      uint32_t w1 = (uint32_t)f2bf(s[ni][2]) | ((uint32_t)f2bf(s[ni][3]) << 16);
      u32x2 pv = {w0, w1};
      *(u32x2*)(plw + lr * 128 + ((ni * 32 + lg * 8) ^ swz)) = pv;
    }
    __builtin_amdgcn_s_setprio(1);
#pragma unroll
    for (int kh = 0; kh < 2; ++kh) {
      bf16x8 pa = *(const bf16x8*)(plw + lr * 128 + ((kh * 64 + lg * 16) ^ swz));
#pragma unroll
      for (int dt = 0; dt < 4; ++dt)
        oacc[dt] = __builtin_amdgcn_mfma_f32_16x16x32_bf16(pa, vb[kh][dt], oacc[dt], 0, 0, 0);
    }
    __builtin_amdgcn_s_setprio(0);

    // prefetch next V tile (cover = next tile's QK^T + softmax)
    if (t < 15) LOAD_VB((t + 1) * 64);

    // rotate bias prefetch registers
    if (t < 14) {
#pragma unroll
      for (int z = 0; z < 4; ++z) { bcur[z] = bnext[z]; bnext[z] = bnew[z]; }
    } else {
#pragma unroll
      for (int z = 0; z < 4; ++z) bcur[z] = bnext[z];
    }
  }

  // normalize + store O bf16 [B,L,D]; inv broadcast like al
  float inv = 1.0f / lrow;
  f32x4 iv;
#pragma unroll
  for (int j = 0; j < 4; ++j) iv[j] = __shfl(inv, (lane & 48) | (lg * 4 + j));
  const int bg = bh / 12, h = bh % 12;
#pragma unroll
  for (int j = 0; j < 4; ++j) {
    int row = qr + lg * 4 + j;
#pragma unroll
    for (int dt = 0; dt < 4; ++dt) {
      gO[(size_t)(bg * 1024 + row) * 768 + h * 64 + dt * 16 + lr] =
          f2bf(oacc[dt][j] * iv[j]);
    }
  }
#undef LOAD_KB
#undef LOAD_VB
#undef BIAS_LOAD
}

// ---------------- GEMM2: out = O @ w_out^T + b_out (fp32 out), 64x64 tiles --
__global__ __launch_bounds__(256) void k_gemm_out(
    const u16* __restrict__ Ob, const u16* __restrict__ Wb,
    const float* __restrict__ b_out, float* __restrict__ out) {
  __shared__ u16 As[64 * 64];
  __shared__ u16 Bs[64 * 64];
  const int tid = threadIdx.x;
  const int lane = tid & 63;
  const int w = tid >> 6;
  const int wm = (w >> 1) * 32;
  const int wn = (w & 1) * 32;
  const int lr = lane & 15;
  const int lg = lane >> 4;
  const int m0 = blockIdx.x * 64;
  const int n0 = blockIdx.y * 64;

  f32x4 acc[2][2];
#pragma unroll
  for (int i = 0; i < 2; ++i)
#pragma unroll
    for (int j = 0; j < 2; ++j) acc[i][j] = (f32x4){0.f, 0.f, 0.f, 0.f};

  for (int kt = 0; kt < 12; ++kt) {
    __syncthreads();
#pragma unroll
    for (int i = 0; i < 2; ++i) {
      int seg = i * 256 + tid;
      int row = seg >> 3;
      int sl = (seg & 7) ^ (row & 7);
      gll16(Ob + (size_t)(m0 + row) * 768 + kt * 64 + sl * 8, (char*)As + seg * 16);
      gll16(Wb + (size_t)(n0 + row) * 768 + kt * 64 + sl * 8, (char*)Bs + seg * 16);
    }
    __syncthreads();
#pragma unroll
    for (int kh = 0; kh < 2; ++kh) {
      bf16x8 af[2], bfr[2];
#pragma unroll
      for (int t = 0; t < 2; ++t) {
        int ra = wm + t * 16 + lr;
        af[t] = *(const bf16x8*)((const char*)As + ra * 128 +
                                 ((kh * 64 + lg * 16) ^ ((ra & 7) << 4)));
        int rb = wn + t * 16 + lr;
        bfr[t] = *(const bf16x8*)((const char*)Bs + rb * 128 +
                                  ((kh * 64 + lg * 16) ^ ((rb & 7) << 4)));
      }
#pragma unroll
      for (int mi = 0; mi < 2; ++mi)
#pragma unroll
        for (int ni = 0; ni < 2; ++ni)
          acc[mi][ni] = __builtin_amdgcn_mfma_f32_16x16x32_bf16(
              af[mi], bfr[ni], acc[mi][ni], 0, 0, 0);
    }
  }
#pragma unroll
  for (int ni = 0; ni < 2; ++ni) {
    int n = n0 + wn + ni * 16 + lr;
    float bias = b_out[n];
#pragma unroll
    for (int mi = 0; mi < 2; ++mi) {
#pragma unroll
      for (int j = 0; j < 4; ++j) {
        int m = m0 + wm + mi * 16 + lg * 4 + j;
        out[(size_t)m * 768 + n] = acc[mi][ni][j] + bias;
      }
    }
  }
}

extern "C" void kernel_launch(void* const* d_in, const int* in_sizes, int n_in,
                              void* d_out, int out_size, void* d_ws, size_t ws_size,
                              hipStream_t stream) {
  const float* x = (const float*)d_in[0];
  const float* attn_bias = (const float*)d_in[1];
  const float* w_in = (const float*)d_in[2];
  const float* b_in = (const float*)d_in[3];
  const float* w_out = (const float*)d_in[4];
  const float* b_out = (const float*)d_in[5];
  float* out = (float*)d_out;

  char* ws = (char*)d_ws;
  size_t off = 0;
  u16* xb = (u16*)(ws + off);  off += (size_t)M_ * D_ * 2;
  u16* wib = (u16*)(ws + off); off += (size_t)N3_ * D_ * 2;
  u16* wob = (u16*)(ws + off); off += (size_t)D_ * D_ * 2;
  u16* q = (u16*)(ws + off);   off += (size_t)48 * 1024 * 64 * 2;
  u16* k = (u16*)(ws + off);   off += (size_t)48 * 1024 * 64 * 2;
  u16* v = (u16*)(ws + off);   off += (size_t)48 * 1024 * 64 * 2;
  u16* vt = (u16*)(ws + off);  off += (size_t)48 * 1024 * 64 * 2;
  u16* ob = (u16*)(ws + off);  off += (size_t)M_ * D_ * 2;

  const int na4 = (M_ * D_) / 4;
  const int nb4 = (N3_ * D_) / 4;
  const int nc4 = (D_ * D_) / 4;
  k_cvt3<<<(na4 + nb4 + nc4 + 255) / 256, 256, 0, stream>>>(
      x, xb, na4, w_in, wib, nb4, w_out, wob, nc4);
  k_gemm_qkv<<<dim3(32, 18), 256, 0, stream>>>(xb, wib, b_in, q, k, v);
  k_transpose<<<768, 256, 0, stream>>>(v, vt);
  k_attn<<<768, 256, 0, stream>>>(q, k, vt, attn_bias, ob);
  k_gemm_out<<<dim3(64, 12), 256, 0, stream>>>(ob, wob, b_out, out);
}

// Round 6
// 125.162 us; speedup vs baseline: 1.3535x; 1.3535x over previous
//
#include <hip/hip_runtime.h>
#include <hip/hip_bf16.h>
#include <stdint.h>

// Problem constants
#define B_ 4
#define L_ 1024
#define D_ 768
#define H_ 12
#define HD_ 64
#define M_ 4096     // B*L
#define N3_ 2304    // 3*D

typedef float f32x4 __attribute__((ext_vector_type(4)));
typedef float f32x4v __attribute__((ext_vector_type(4)));
typedef short bf16x8 __attribute__((ext_vector_type(8)));
typedef unsigned short u16;
typedef u16 u16x8 __attribute__((ext_vector_type(8)));
typedef u16 u16x4 __attribute__((ext_vector_type(4)));
typedef uint32_t u32x2 __attribute__((ext_vector_type(2)));

#define AS3 __attribute__((address_space(3)))
#define AS1 __attribute__((address_space(1)))

__device__ __forceinline__ void gll16(const void* g, void* l) {
  __builtin_amdgcn_global_load_lds((const AS1 void*)g, (AS3 void*)l, 16, 0, 0);
}

// fp32 -> bf16 round-to-nearest-even (finite data)
__device__ __forceinline__ u16 f2bf(float f) {
  uint32_t u = __builtin_bit_cast(uint32_t, f);
  u += 0x7fffu + ((u >> 16) & 1u);
  return (u16)(u >> 16);
}

// ---------------- fused conversion kernel (3 tensors, fp32 -> bf16) ---------
__global__ void k_cvt3(const float* __restrict__ a, u16* __restrict__ ao, int na4,
                       const float* __restrict__ b, u16* __restrict__ bo, int nb4,
                       const float* __restrict__ c, u16* __restrict__ co, int nc4) {
  int i = blockIdx.x * 256 + threadIdx.x;
  const float* src;
  u16* dst;
  if (i < na4) {
    src = a; dst = ao;
  } else if (i < na4 + nb4) {
    src = b; dst = bo; i -= na4;
  } else if (i < na4 + nb4 + nc4) {
    src = c; dst = co; i -= na4 + nb4;
  } else {
    return;
  }
  f32x4v v = ((const f32x4v*)src)[i];
  u16x4 o;
  o.x = f2bf(v.x); o.y = f2bf(v.y); o.z = f2bf(v.z); o.w = f2bf(v.w);
  ((u16x4*)dst)[i] = o;
}

// ---------------- GEMM1: qkv = x @ w_in^T + b_in -> Q,K,V bf16 [B,H,L,64] ----
__global__ __launch_bounds__(256) void k_gemm_qkv(
    const u16* __restrict__ Xb, const u16* __restrict__ Wb,
    const float* __restrict__ b_in,
    u16* __restrict__ gQ, u16* __restrict__ gK, u16* __restrict__ gV) {
  __shared__ u16 As[128 * 64];
  __shared__ u16 Bs[128 * 64];
  const int tid = threadIdx.x;
  const int lane = tid & 63;
  const int w = tid >> 6;
  const int wm = (w >> 1) * 64;
  const int wn = (w & 1) * 64;
  const int lr = lane & 15;
  const int lg = lane >> 4;
  const int m0 = blockIdx.x * 128;
  const int n0 = blockIdx.y * 128;

  f32x4 acc[4][4];
#pragma unroll
  for (int i = 0; i < 4; ++i)
#pragma unroll
    for (int j = 0; j < 4; ++j) acc[i][j] = (f32x4){0.f, 0.f, 0.f, 0.f};

  for (int kt = 0; kt < 12; ++kt) {
    __syncthreads();
#pragma unroll
    for (int i = 0; i < 4; ++i) {
      int seg = i * 256 + tid;
      int row = seg >> 3;
      int sl = (seg & 7) ^ (row & 7);
      gll16(Xb + (size_t)(m0 + row) * 768 + kt * 64 + sl * 8, (char*)As + seg * 16);
      gll16(Wb + (size_t)(n0 + row) * 768 + kt * 64 + sl * 8, (char*)Bs + seg * 16);
    }
    __syncthreads();
#pragma unroll
    for (int kh = 0; kh < 2; ++kh) {
      bf16x8 af[4], bfr[4];
#pragma unroll
      for (int t = 0; t < 4; ++t) {
        int ra = wm + t * 16 + lr;
        af[t] = *(const bf16x8*)((const char*)As + ra * 128 +
                                 ((kh * 64 + lg * 16) ^ ((ra & 7) << 4)));
        int rb = wn + t * 16 + lr;
        bfr[t] = *(const bf16x8*)((const char*)Bs + rb * 128 +
                                  ((kh * 64 + lg * 16) ^ ((rb & 7) << 4)));
      }
#pragma unroll
      for (int mi = 0; mi < 4; ++mi)
#pragma unroll
        for (int ni = 0; ni < 4; ++ni)
          acc[mi][ni] = __builtin_amdgcn_mfma_f32_16x16x32_bf16(
              af[mi], bfr[ni], acc[mi][ni], 0, 0, 0);
    }
  }
  // epilogue: +b_in, scale q, scatter to [B,H,L,64] bf16
  const int sec = blockIdx.y / 6;  // 0=q,1=k,2=v
  u16* dst = sec == 0 ? gQ : (sec == 1 ? gK : gV);
  const float scale = sec == 0 ? 0.125f : 1.0f;
#pragma unroll
  for (int ni = 0; ni < 4; ++ni) {
    int e = n0 + wn + ni * 16 + lr;  // 0..2303
    float bias = b_in[e];
    int es = e - sec * 768;
    int h = es >> 6, d = es & 63;
#pragma unroll
    for (int mi = 0; mi < 4; ++mi) {
#pragma unroll
      for (int j = 0; j < 4; ++j) {
        int m = m0 + wm + mi * 16 + lg * 4 + j;
        int bb = m >> 10, lq = m & 1023;
        float vv = (acc[mi][ni][j] + bias) * scale;
        dst[(size_t)((bb * 12 + h) * 1024 + lq) * 64 + d] = f2bf(vv);
      }
    }
  }
}

// ---------------- pack K,V into MFMA-fragment order -------------------------
// Kp[bh][t][kh][ni][lane][8]: elem j = K[bh][t*64+ni*16+(lane&15)][kh*32+(lane>>4)*8+j]
// Vp[bh][t][kh][dt][lane][8]: elem j = V[bh][t*64+kh*32+(lane>>4)*8+j][dt*16+(lane&15)]
// Attention then loads fragments as 64-lane contiguous 1KB (fully coalesced).
__global__ __launch_bounds__(256) void k_pack(const u16* __restrict__ K,
                                              const u16* __restrict__ V,
                                              u16* __restrict__ Kp,
                                              u16* __restrict__ Vp) {
  __shared__ u16 tile[64][72];  // V tile, padded
  const int tid = threadIdx.x;
  const int bh = blockIdx.x >> 4, t = blockIdx.x & 15;
  const u16* ksrc = K + ((size_t)bh * 1024 + t * 64) * 64;
  const u16* vsrc = V + ((size_t)bh * 1024 + t * 64) * 64;
  {
    int r = tid >> 2, c0 = (tid & 3) * 16;
    *(u16x8*)&tile[r][c0] = *(const u16x8*)(vsrc + r * 64 + c0);
    *(u16x8*)&tile[r][c0 + 8] = *(const u16x8*)(vsrc + r * 64 + c0 + 8);
  }
  u16* kdst = Kp + (size_t)(bh * 16 + t) * 4096;
#pragma unroll
  for (int i = 0; i < 2; ++i) {
    int fid = i * 256 + tid;  // [0,512)
    int kh = fid >> 8, ni = (fid >> 6) & 3, lane = fid & 63;
    int lr = lane & 15, lg = lane >> 4;
    u16x8 v = *(const u16x8*)(ksrc + (ni * 16 + lr) * 64 + kh * 32 + lg * 8);
    *(u16x8*)(kdst + fid * 8) = v;
  }
  __syncthreads();
  u16* vdst = Vp + (size_t)(bh * 16 + t) * 4096;
#pragma unroll
  for (int i = 0; i < 2; ++i) {
    int fid = i * 256 + tid;
    int kh = fid >> 8, dt = (fid >> 6) & 3, lane = fid & 63;
    int lr = lane & 15, lg = lane >> 4;
    u16x8 o;
#pragma unroll
    for (int j = 0; j < 8; ++j) o[j] = tile[kh * 32 + lg * 8 + j][dt * 16 + lr];
    *(u16x8*)(vdst + fid * 8) = o;
  }
}

// ---------------- fused flash attention (kv-split, high-TLP) ----------------
// 1536 blocks x 4 waves. Wave w: q-rows qbase+(w&1)*16.., kv half (w>>1).
// Swapped QK^T -> lane-local softmax. K/V fragments demand-loaded coalesced
// from packed layout (TLP hides L2 latency). Bias depth-1 register prefetch.
// Partner waves (w, w+2) merge online-softmax states once at the end.
__global__ __launch_bounds__(256, 4) void k_attn(
    const u16* __restrict__ gQ, const u16* __restrict__ Kp,
    const u16* __restrict__ Vp, const float* __restrict__ gBias,
    u16* __restrict__ gO) {
  __shared__ f32x4 PlV[4][128];    // per-wave 2KB P bounce
  __shared__ float mg[2][64][18];  // merge area for waves 2,3
  const int tid = threadIdx.x;
  const int lane = tid & 63;
  const int w = tid >> 6;
  const int lr = lane & 15;
  const int lg = lane >> 4;
  // XCD-bijective swizzle: 1536 = 8 XCDs x 192; blocks of one bh stay on one XCD.
  const int lb = (blockIdx.x & 7) * 192 + (blockIdx.x >> 3);
  const int bh = lb >> 5;
  const int qbase = (lb & 31) * 32;
  const int qr = qbase + (w & 1) * 16;  // wave's q-row base; lane's q = qr+lr
  const int kvh = w >> 1;               // kv half: tiles kvh*8 .. kvh*8+7

  const u16* kp = Kp + (size_t)bh * 65536;  // 16 tiles * 4096 u16
  const u16* vp = Vp + (size_t)bh * 65536;
  const float* bline = gBias + (size_t)(bh * 1024 + qr + lr) * 1024 + kvh * 512;

#define BIAS_LOAD(dst, c0)                                                     \
  do {                                                                         \
    _Pragma("unroll") for (int ni_ = 0; ni_ < 4; ++ni_)                        \
      dst[ni_] = *(const f32x4*)(bline + (c0) + ni_ * 16 + lg * 4);            \
  } while (0)

  // Q as B-operand: rows q = qr+lr (pre-scaled by 1/8 in GEMM1)
  bf16x8 qa[2];
#pragma unroll
  for (int kh = 0; kh < 2; ++kh)
    qa[kh] = *(const bf16x8*)(gQ + (size_t)(bh * 1024 + qr + lr) * 64 + kh * 32 + lg * 8);

  f32x4 oacc[4];
#pragma unroll
  for (int dt = 0; dt < 4; ++dt) oacc[dt] = (f32x4){0.f, 0.f, 0.f, 0.f};
  float mrow = -1e30f, lrow = 0.f;

  char* plw = (char*)PlV[w];
  const int swz = (lr & 7) << 4;

  f32x4 bcur[4], bnext[4];
  BIAS_LOAD(bcur, 0);

  for (int t = 0; t < 8; ++t) {
    const int tt = kvh * 8 + t;
    // K fragments: 8 coalesced 1KB loads (demand; TLP hides L2)
    bf16x8 kb[2][4];
#pragma unroll
    for (int kh = 0; kh < 2; ++kh)
#pragma unroll
      for (int ni = 0; ni < 4; ++ni)
        kb[kh][ni] = *(const bf16x8*)(kp + (size_t)(tt * 8 + kh * 4 + ni) * 512 + lane * 8);

    // S^T = K Q^T : s[ni][j] = S[kv = tt*64+ni*16+lg*4+j][q = qr+lr]
    f32x4 s[4];
#pragma unroll
    for (int ni = 0; ni < 4; ++ni) s[ni] = (f32x4){0.f, 0.f, 0.f, 0.f};
    __builtin_amdgcn_s_setprio(1);
#pragma unroll
    for (int kh = 0; kh < 2; ++kh)
#pragma unroll
      for (int ni = 0; ni < 4; ++ni)
        s[ni] = __builtin_amdgcn_mfma_f32_16x16x32_bf16(kb[kh][ni], qa[kh], s[ni], 0, 0, 0);
    __builtin_amdgcn_s_setprio(0);

    // V fragments issued now: latency covered by softmax below
    bf16x8 vb[2][4];
#pragma unroll
    for (int kh = 0; kh < 2; ++kh)
#pragma unroll
      for (int dt = 0; dt < 4; ++dt)
        vb[kh][dt] = *(const bf16x8*)(vp + (size_t)(tt * 8 + kh * 4 + dt) * 512 + lane * 8);

    // + bias (depth-1 prefetch), then issue next tile's bias
#pragma unroll
    for (int ni = 0; ni < 4; ++ni) s[ni] += bcur[ni];
    if (t < 7) BIAS_LOAD(bnext, (t + 1) * 64);

    // lane-local online softmax for q-row (qr+lr)
    float mx0 = fmaxf(fmaxf(s[0][0], s[0][1]), fmaxf(s[0][2], s[0][3]));
    float mx1 = fmaxf(fmaxf(s[1][0], s[1][1]), fmaxf(s[1][2], s[1][3]));
    float mx2 = fmaxf(fmaxf(s[2][0], s[2][1]), fmaxf(s[2][2], s[2][3]));
    float mx3 = fmaxf(fmaxf(s[3][0], s[3][1]), fmaxf(s[3][2], s[3][3]));
    float vmax = fmaxf(fmaxf(mx0, mx1), fmaxf(mx2, mx3));
    vmax = fmaxf(vmax, __shfl_xor(vmax, 16));
    vmax = fmaxf(vmax, __shfl_xor(vmax, 32));
    float mnew = fmaxf(mrow, vmax);
    float al = __expf(mrow - mnew);
    mrow = mnew;
#pragma unroll
    for (int ni = 0; ni < 4; ++ni)
#pragma unroll
      for (int j = 0; j < 4; ++j) s[ni][j] = __expf(s[ni][j] - mnew);
    float r0 = (s[0][0] + s[0][1]) + (s[0][2] + s[0][3]);
    float r1 = (s[1][0] + s[1][1]) + (s[1][2] + s[1][3]);
    float r2 = (s[2][0] + s[2][1]) + (s[2][2] + s[2][3]);
    float r3 = (s[3][0] + s[3][1]) + (s[3][2] + s[3][3]);
    float rs = (r0 + r1) + (r2 + r3);
    rs += __shfl_xor(rs, 16);
    rs += __shfl_xor(rs, 32);
    lrow = lrow * al + rs;

    // broadcast al from lane (lr = q) to the oacc owners (q = lg*4+j)
    f32x4 av;
#pragma unroll
    for (int j = 0; j < 4; ++j) av[j] = __shfl(al, (lane & 48) | (lg * 4 + j));
#pragma unroll
    for (int dt = 0; dt < 4; ++dt) oacc[dt] *= av;

    // P pack -> per-wave swizzled LDS (b64), read back as A-fragment, PV
#pragma unroll
    for (int ni = 0; ni < 4; ++ni) {
      uint32_t w0 = (uint32_t)f2bf(s[ni][0]) | ((uint32_t)f2bf(s[ni][1]) << 16);
      uint32_t w1 = (uint32_t)f2bf(s[ni][2]) | ((uint32_t)f2bf(s[ni][3]) << 16);
      u32x2 pv = {w0, w1};
      *(u32x2*)(plw + lr * 128 + ((ni * 32 + lg * 8) ^ swz)) = pv;
    }
    __builtin_amdgcn_s_setprio(1);
#pragma unroll
    for (int kh = 0; kh < 2; ++kh) {
      bf16x8 pa = *(const bf16x8*)(plw + lr * 128 + ((kh * 64 + lg * 16) ^ swz));
#pragma unroll
      for (int dt = 0; dt < 4; ++dt)
        oacc[dt] = __builtin_amdgcn_mfma_f32_16x16x32_bf16(pa, vb[kh][dt], oacc[dt], 0, 0, 0);
    }
    __builtin_amdgcn_s_setprio(0);

    // rotate bias prefetch
    if (t < 7) {
#pragma unroll
      for (int z = 0; z < 4; ++z) bcur[z] = bnext[z];
    }
  }

  // ---- merge partner waves (w, w+2): same q-rows, complementary kv halves --
  if (w >= 2) {
    float* p = mg[w - 2][lane];
#pragma unroll
    for (int dt = 0; dt < 4; ++dt)
#pragma unroll
      for (int j = 0; j < 4; ++j) p[dt * 4 + j] = oacc[dt][j];
    p[16] = mrow;
    p[17] = lrow;
  }
  __syncthreads();
  if (w < 2) {
    const float* p = mg[w][lane];
    float pm = p[16], pl = p[17];
    float m = fmaxf(mrow, pm);
    float a = __expf(mrow - m);
    float b = __expf(pm - m);
    float l = lrow * a + pl * b;
    float inv = 1.0f / l;
    f32x4 avv, bvv, ivv;
#pragma unroll
    for (int j = 0; j < 4; ++j) {
      int src = (lane & 48) | (lg * 4 + j);
      avv[j] = __shfl(a, src);
      bvv[j] = __shfl(b, src);
      ivv[j] = __shfl(inv, src);
    }
    const int bg = bh / 12, h = bh % 12;
#pragma unroll
    for (int j = 0; j < 4; ++j) {
      int row = qr + lg * 4 + j;
#pragma unroll
      for (int dt = 0; dt < 4; ++dt) {
        float o = (oacc[dt][j] * avv[j] + mg[w][lane][dt * 4 + j] * bvv[j]) * ivv[j];
        gO[(size_t)(bg * 1024 + row) * 768 + h * 64 + dt * 16 + lr] = f2bf(o);
      }
    }
  }
#undef BIAS_LOAD
}

// ---------------- GEMM2: out = O @ w_out^T + b_out (fp32 out), 64x64 tiles --
__global__ __launch_bounds__(256) void k_gemm_out(
    const u16* __restrict__ Ob, const u16* __restrict__ Wb,
    const float* __restrict__ b_out, float* __restrict__ out) {
  __shared__ u16 As[64 * 64];
  __shared__ u16 Bs[64 * 64];
  const int tid = threadIdx.x;
  const int lane = tid & 63;
  const int w = tid >> 6;
  const int wm = (w >> 1) * 32;
  const int wn = (w & 1) * 32;
  const int lr = lane & 15;
  const int lg = lane >> 4;
  const int m0 = blockIdx.x * 64;
  const int n0 = blockIdx.y * 64;

  f32x4 acc[2][2];
#pragma unroll
  for (int i = 0; i < 2; ++i)
#pragma unroll
    for (int j = 0; j < 2; ++j) acc[i][j] = (f32x4){0.f, 0.f, 0.f, 0.f};

  for (int kt = 0; kt < 12; ++kt) {
    __syncthreads();
#pragma unroll
    for (int i = 0; i < 2; ++i) {
      int seg = i * 256 + tid;
      int row = seg >> 3;
      int sl = (seg & 7) ^ (row & 7);
      gll16(Ob + (size_t)(m0 + row) * 768 + kt * 64 + sl * 8, (char*)As + seg * 16);
      gll16(Wb + (size_t)(n0 + row) * 768 + kt * 64 + sl * 8, (char*)Bs + seg * 16);
    }
    __syncthreads();
#pragma unroll
    for (int kh = 0; kh < 2; ++kh) {
      bf16x8 af[2], bfr[2];
#pragma unroll
      for (int t = 0; t < 2; ++t) {
        int ra = wm + t * 16 + lr;
        af[t] = *(const bf16x8*)((const char*)As + ra * 128 +
                                 ((kh * 64 + lg * 16) ^ ((ra & 7) << 4)));
        int rb = wn + t * 16 + lr;
        bfr[t] = *(const bf16x8*)((const char*)Bs + rb * 128 +
                                  ((kh * 64 + lg * 16) ^ ((rb & 7) << 4)));
      }
#pragma unroll
      for (int mi = 0; mi < 2; ++mi)
#pragma unroll
        for (int ni = 0; ni < 2; ++ni)
          acc[mi][ni] = __builtin_amdgcn_mfma_f32_16x16x32_bf16(
              af[mi], bfr[ni], acc[mi][ni], 0, 0, 0);
    }
  }
#pragma unroll
  for (int ni = 0; ni < 2; ++ni) {
    int n = n0 + wn + ni * 16 + lr;
    float bias = b_out[n];
#pragma unroll
    for (int mi = 0; mi < 2; ++mi) {
#pragma unroll
      for (int j = 0; j < 4; ++j) {
        int m = m0 + wm + mi * 16 + lg * 4 + j;
        out[(size_t)m * 768 + n] = acc[mi][ni][j] + bias;
      }
    }
  }
}

extern "C" void kernel_launch(void* const* d_in, const int* in_sizes, int n_in,
                              void* d_out, int out_size, void* d_ws, size_t ws_size,
                              hipStream_t stream) {
  const float* x = (const float*)d_in[0];
  const float* attn_bias = (const float*)d_in[1];
  const float* w_in = (const float*)d_in[2];
  const float* b_in = (const float*)d_in[3];
  const float* w_out = (const float*)d_in[4];
  const float* b_out = (const float*)d_in[5];
  float* out = (float*)d_out;

  char* ws = (char*)d_ws;
  size_t off = 0;
  u16* xb = (u16*)(ws + off);  off += (size_t)M_ * D_ * 2;
  u16* wib = (u16*)(ws + off); off += (size_t)N3_ * D_ * 2;
  u16* wob = (u16*)(ws + off); off += (size_t)D_ * D_ * 2;
  u16* q = (u16*)(ws + off);   off += (size_t)48 * 1024 * 64 * 2;
  u16* k = (u16*)(ws + off);   off += (size_t)48 * 1024 * 64 * 2;
  u16* v = (u16*)(ws + off);   off += (size_t)48 * 1024 * 64 * 2;
  u16* kp = (u16*)(ws + off);  off += (size_t)48 * 1024 * 64 * 2;
  u16* vp = (u16*)(ws + off);  off += (size_t)48 * 1024 * 64 * 2;
  u16* ob = (u16*)(ws + off);  off += (size_t)M_ * D_ * 2;

  const int na4 = (M_ * D_) / 4;
  const int nb4 = (N3_ * D_) / 4;
  const int nc4 = (D_ * D_) / 4;
  k_cvt3<<<(na4 + nb4 + nc4 + 255) / 256, 256, 0, stream>>>(
      x, xb, na4, w_in, wib, nb4, w_out, wob, nc4);
  k_gemm_qkv<<<dim3(32, 18), 256, 0, stream>>>(xb, wib, b_in, q, k, v);
  k_pack<<<768, 256, 0, stream>>>(k, v, kp, vp);
  k_attn<<<1536, 256, 0, stream>>>(q, kp, vp, attn_bias, ob);
  k_gemm_out<<<dim3(64, 12), 256, 0, stream>>>(ob, wob, b_out, out);
}

// Round 7
// 121.845 us; speedup vs baseline: 1.3904x; 1.0272x over previous
//
#include <hip/hip_runtime.h>
#include <hip/hip_bf16.h>
#include <stdint.h>

// Problem constants
#define B_ 4
#define L_ 1024
#define D_ 768
#define H_ 12
#define HD_ 64
#define M_ 4096     // B*L
#define N3_ 2304    // 3*D

typedef float f32x4 __attribute__((ext_vector_type(4)));
typedef float f32x4v __attribute__((ext_vector_type(4)));
typedef short bf16x8 __attribute__((ext_vector_type(8)));
typedef unsigned short u16;
typedef u16 u16x8 __attribute__((ext_vector_type(8)));
typedef u16 u16x4 __attribute__((ext_vector_type(4)));
typedef uint32_t u32x2 __attribute__((ext_vector_type(2)));

#define AS3 __attribute__((address_space(3)))
#define AS1 __attribute__((address_space(1)))

__device__ __forceinline__ void gll16(const void* g, void* l) {
  __builtin_amdgcn_global_load_lds((const AS1 void*)g, (AS3 void*)l, 16, 0, 0);
}

// fp32 -> bf16 round-to-nearest-even (finite data)
__device__ __forceinline__ u16 f2bf(float f) {
  uint32_t u = __builtin_bit_cast(uint32_t, f);
  u += 0x7fffu + ((u >> 16) & 1u);
  return (u16)(u >> 16);
}

// ---------------- fused conversion kernel (3 tensors, fp32 -> bf16) ---------
__global__ void k_cvt3(const float* __restrict__ a, u16* __restrict__ ao, int na4,
                       const float* __restrict__ b, u16* __restrict__ bo, int nb4,
                       const float* __restrict__ c, u16* __restrict__ co, int nc4) {
  int i = blockIdx.x * 256 + threadIdx.x;
  const float* src;
  u16* dst;
  if (i < na4) {
    src = a; dst = ao;
  } else if (i < na4 + nb4) {
    src = b; dst = bo; i -= na4;
  } else if (i < na4 + nb4 + nc4) {
    src = c; dst = co; i -= na4 + nb4;
  } else {
    return;
  }
  f32x4v v = ((const f32x4v*)src)[i];
  u16x4 o;
  o.x = f2bf(v.x); o.y = f2bf(v.y); o.z = f2bf(v.z); o.w = f2bf(v.w);
  ((u16x4*)dst)[i] = o;
}

// ---------------- GEMM1: qkv = x @ w_in^T + b_in -> Q,K,V bf16 [B,H,L,64] ----
__global__ __launch_bounds__(256) void k_gemm_qkv(
    const u16* __restrict__ Xb, const u16* __restrict__ Wb,
    const float* __restrict__ b_in,
    u16* __restrict__ gQ, u16* __restrict__ gK, u16* __restrict__ gV) {
  __shared__ u16 As[128 * 64];
  __shared__ u16 Bs[128 * 64];
  const int tid = threadIdx.x;
  const int lane = tid & 63;
  const int w = tid >> 6;
  const int wm = (w >> 1) * 64;
  const int wn = (w & 1) * 64;
  const int lr = lane & 15;
  const int lg = lane >> 4;
  const int m0 = blockIdx.x * 128;
  const int n0 = blockIdx.y * 128;

  f32x4 acc[4][4];
#pragma unroll
  for (int i = 0; i < 4; ++i)
#pragma unroll
    for (int j = 0; j < 4; ++j) acc[i][j] = (f32x4){0.f, 0.f, 0.f, 0.f};

  for (int kt = 0; kt < 12; ++kt) {
    __syncthreads();
#pragma unroll
    for (int i = 0; i < 4; ++i) {
      int seg = i * 256 + tid;
      int row = seg >> 3;
      int sl = (seg & 7) ^ (row & 7);
      gll16(Xb + (size_t)(m0 + row) * 768 + kt * 64 + sl * 8, (char*)As + seg * 16);
      gll16(Wb + (size_t)(n0 + row) * 768 + kt * 64 + sl * 8, (char*)Bs + seg * 16);
    }
    __syncthreads();
#pragma unroll
    for (int kh = 0; kh < 2; ++kh) {
      bf16x8 af[4], bfr[4];
#pragma unroll
      for (int t = 0; t < 4; ++t) {
        int ra = wm + t * 16 + lr;
        af[t] = *(const bf16x8*)((const char*)As + ra * 128 +
                                 ((kh * 64 + lg * 16) ^ ((ra & 7) << 4)));
        int rb = wn + t * 16 + lr;
        bfr[t] = *(const bf16x8*)((const char*)Bs + rb * 128 +
                                  ((kh * 64 + lg * 16) ^ ((rb & 7) << 4)));
      }
#pragma unroll
      for (int mi = 0; mi < 4; ++mi)
#pragma unroll
        for (int ni = 0; ni < 4; ++ni)
          acc[mi][ni] = __builtin_amdgcn_mfma_f32_16x16x32_bf16(
              af[mi], bfr[ni], acc[mi][ni], 0, 0, 0);
    }
  }
  // epilogue: +b_in, scale q, scatter to [B,H,L,64] bf16
  const int sec = blockIdx.y / 6;  // 0=q,1=k,2=v
  u16* dst = sec == 0 ? gQ : (sec == 1 ? gK : gV);
  const float scale = sec == 0 ? 0.125f : 1.0f;
#pragma unroll
  for (int ni = 0; ni < 4; ++ni) {
    int e = n0 + wn + ni * 16 + lr;  // 0..2303
    float bias = b_in[e];
    int es = e - sec * 768;
    int h = es >> 6, d = es & 63;
#pragma unroll
    for (int mi = 0; mi < 4; ++mi) {
#pragma unroll
      for (int j = 0; j < 4; ++j) {
        int m = m0 + wm + mi * 16 + lg * 4 + j;
        int bb = m >> 10, lq = m & 1023;
        float vv = (acc[mi][ni][j] + bias) * scale;
        dst[(size_t)((bb * 12 + h) * 1024 + lq) * 64 + d] = f2bf(vv);
      }
    }
  }
}

// ---------------- V transpose: [B,H,L,64] -> [B,H,64,L] ---------------------
__global__ __launch_bounds__(256) void k_transpose(const u16* __restrict__ V,
                                                   u16* __restrict__ Vt) {
  __shared__ u16 t[64][66];
  const int tid = threadIdx.x;
  const int bh = blockIdx.x >> 4;
  const int kv0 = (blockIdx.x & 15) * 64;
  {
    int r = tid >> 2, c0 = (tid & 3) * 16;
    const u16* src = V + (size_t)(bh * 1024 + kv0 + r) * 64 + c0;
#pragma unroll
    for (int p = 0; p < 2; ++p) {
      u16x8 x = *(const u16x8*)(src + p * 8);
#pragma unroll
      for (int e = 0; e < 8; ++e) t[r][c0 + p * 8 + e] = x[e];
    }
  }
  __syncthreads();
  {
    int d = tid >> 2, k0 = (tid & 3) * 16;
    u16* dst = Vt + (size_t)(bh * 64 + d) * 1024 + kv0 + k0;
#pragma unroll
    for (int p = 0; p < 2; ++p) {
      u16x8 o;
#pragma unroll
      for (int e = 0; e < 8; ++e) o[e] = t[k0 + p * 8 + e][d];
      *(u16x8*)(dst + p * 8) = o;
    }
  }
}

// ---------------- fused flash attention (all-gll16 staged) ------------------
// Swapped QK^T -> lane-local softmax. K, V, AND bias ALL staged to LDS via
// global_load_lds (no destination VGPR -> compiler cannot sink/demote the
// prefetch, no compiler vmcnt waits in the loop). Double-buffered; stage for
// tile t+1 issued at top of tile t; one __syncthreads per tile whose vmcnt(0)
// drain is exactly the stage completion we need (issued a full tile earlier).
__global__ __launch_bounds__(256) void k_attn(
    const u16* __restrict__ gQ, const u16* __restrict__ gK,
    const u16* __restrict__ gVt, const float* __restrict__ gBias,
    u16* __restrict__ gO) {
  __shared__ u16 Ks[2][64 * 64];   // 16 KB  [kv][d] rows 128B, src pre-swizzled
  __shared__ u16 Vs[2][64 * 64];   // 16 KB  [d][kv]
  __shared__ float Bi[2][64 * 64]; // 32 KB  [q][kv] fp32, slot-swizzled
  __shared__ f32x4 PlV[4][128];    // 8 KB   per-wave P bounce
  const int tid = threadIdx.x;
  const int lane = tid & 63;
  const int w = tid >> 6;
  const int lr = lane & 15;
  const int lg = lane >> 4;
  // XCD-bijective swizzle: 768 = 8 XCDs x 96; the 16 q-blocks sharing one
  // (b,h)'s K/V land on one XCD -> K/V stay L2-resident.
  const int lb = (blockIdx.x & 7) * 96 + (blockIdx.x >> 3);
  const int bh = lb >> 4;
  const int q0 = (lb & 15) * 64;
  const int qr = q0 + w * 16;  // wave's q-row base; lane's q-row = qr + lr

// Stage one full tile (K 8KB + V 8KB + bias 16KB) via gll16.
// K/V: 2 instr/thread each; bias: 4 instr/thread. LDS dest linear, src swizzled.
#define STAGE(buf, kv0)                                                        \
  do {                                                                         \
    _Pragma("unroll") for (int i_ = 0; i_ < 2; ++i_) {                         \
      int seg_ = i_ * 256 + tid;                                               \
      int row_ = seg_ >> 3;                                                    \
      int sl_ = (seg_ & 7) ^ (row_ & 7);                                       \
      gll16(gK + (size_t)(bh * 1024 + (kv0) + row_) * 64 + sl_ * 8,            \
            (char*)Ks[buf] + seg_ * 16);                                       \
      gll16(gVt + (size_t)(bh * 64 + row_) * 1024 + (kv0) + sl_ * 8,           \
            (char*)Vs[buf] + seg_ * 16);                                       \
    }                                                                          \
    _Pragma("unroll") for (int i_ = 0; i_ < 4; ++i_) {                         \
      int seg_ = i_ * 256 + tid;                                               \
      int qrow_ = seg_ >> 4;                                                   \
      int c_ = (seg_ & 15) ^ (qrow_ & 7);                                      \
      gll16(gBias + (size_t)(bh * 1024 + q0 + qrow_) * 1024 + (kv0) + c_ * 4,  \
            (char*)Bi[buf] + seg_ * 16);                                       \
    }                                                                          \
  } while (0)

  // Q as B-operand: rows q = qr+lr (pre-scaled by 1/8 in GEMM1)
  bf16x8 qa[2];
#pragma unroll
  for (int kh = 0; kh < 2; ++kh)
    qa[kh] = *(const bf16x8*)(gQ + (size_t)(bh * 1024 + qr + lr) * 64 + kh * 32 + lg * 8);

  f32x4 oacc[4];
#pragma unroll
  for (int dt = 0; dt < 4; ++dt) oacc[dt] = (f32x4){0.f, 0.f, 0.f, 0.f};
  float mrow = -1e30f, lrow = 0.f;

  char* plw = (char*)PlV[w];
  const int swz = (lr & 7) << 4;

  STAGE(0, 0);
  __syncthreads();  // vmcnt(0): stage 0 landed

  for (int t = 0; t < 16; ++t) {
    const int cur = t & 1;
    if (t < 15) STAGE(cur ^ 1, (t + 1) * 64);  // in flight across whole tile

    // S^T = K Q^T : s[ni][j] = S[kv = ni*16+lg*4+j][q = qr+lr]
    f32x4 s[4];
#pragma unroll
    for (int ni = 0; ni < 4; ++ni) s[ni] = (f32x4){0.f, 0.f, 0.f, 0.f};
    __builtin_amdgcn_s_setprio(1);
#pragma unroll
    for (int kh = 0; kh < 2; ++kh)
#pragma unroll
      for (int ni = 0; ni < 4; ++ni) {
        int rk = ni * 16 + lr;
        bf16x8 kb = *(const bf16x8*)((const char*)Ks[cur] + rk * 128 +
                                     ((kh * 64 + lg * 16) ^ ((rk & 7) << 4)));
        s[ni] = __builtin_amdgcn_mfma_f32_16x16x32_bf16(kb, qa[kh], s[ni], 0, 0, 0);
      }
    __builtin_amdgcn_s_setprio(0);

    // + bias from LDS: lane needs bias[q=qr+lr][kv0 + ni*16 + lg*4 + j]
#pragma unroll
    for (int ni = 0; ni < 4; ++ni) {
      f32x4 bv = *(const f32x4*)((const char*)Bi[cur] + (w * 16 + lr) * 256 +
                                 (((ni * 4 + lg) ^ (lr & 7)) << 4));
      s[ni] += bv;
    }

    // lane-local online softmax for q-row (qr+lr)
    float mx0 = fmaxf(fmaxf(s[0][0], s[0][1]), fmaxf(s[0][2], s[0][3]));
    float mx1 = fmaxf(fmaxf(s[1][0], s[1][1]), fmaxf(s[1][2], s[1][3]));
    float mx2 = fmaxf(fmaxf(s[2][0], s[2][1]), fmaxf(s[2][2], s[2][3]));
    float mx3 = fmaxf(fmaxf(s[3][0], s[3][1]), fmaxf(s[3][2], s[3][3]));
    float vmax = fmaxf(fmaxf(mx0, mx1), fmaxf(mx2, mx3));
    vmax = fmaxf(vmax, __shfl_xor(vmax, 16));
    vmax = fmaxf(vmax, __shfl_xor(vmax, 32));
    float mnew = fmaxf(mrow, vmax);
    float al = __expf(mrow - mnew);
    mrow = mnew;
#pragma unroll
    for (int ni = 0; ni < 4; ++ni)
#pragma unroll
      for (int j = 0; j < 4; ++j) s[ni][j] = __expf(s[ni][j] - mnew);
    float r0 = (s[0][0] + s[0][1]) + (s[0][2] + s[0][3]);
    float r1 = (s[1][0] + s[1][1]) + (s[1][2] + s[1][3]);
    float r2 = (s[2][0] + s[2][1]) + (s[2][2] + s[2][3]);
    float r3 = (s[3][0] + s[3][1]) + (s[3][2] + s[3][3]);
    float rs = (r0 + r1) + (r2 + r3);
    rs += __shfl_xor(rs, 16);
    rs += __shfl_xor(rs, 32);
    lrow = lrow * al + rs;

    // broadcast al from lane (lr = q) to the oacc owners (q = lg*4+j)
    f32x4 av;
#pragma unroll
    for (int j = 0; j < 4; ++j) av[j] = __shfl(al, (lane & 48) | (lg * 4 + j));
#pragma unroll
    for (int dt = 0; dt < 4; ++dt) oacc[dt] *= av;

    // P pack -> per-wave swizzled LDS (b64), read back as A-fragment, PV
#pragma unroll
    for (int ni = 0; ni < 4; ++ni) {
      uint32_t w0 = (uint32_t)f2bf(s[ni][0]) | ((uint32_t)f2bf(s[ni][1]) << 16);
      uint32_t w1 = (uint32_t)f2bf(s[ni][2]) | ((uint32_t)f2bf(s[ni][3]) << 16);
      u32x2 pv = {w0, w1};
      *(u32x2*)(plw + lr * 128 + ((ni * 32 + lg * 8) ^ swz)) = pv;
    }
    __builtin_amdgcn_s_setprio(1);
#pragma unroll
    for (int kh = 0; kh < 2; ++kh) {
      bf16x8 pa = *(const bf16x8*)(plw + lr * 128 + ((kh * 64 + lg * 16) ^ swz));
#pragma unroll
      for (int dt = 0; dt < 4; ++dt) {
        int rv = dt * 16 + lr;
        bf16x8 vb = *(const bf16x8*)((const char*)Vs[cur] + rv * 128 +
                                     ((kh * 64 + lg * 16) ^ ((rv & 7) << 4)));
        oacc[dt] = __builtin_amdgcn_mfma_f32_16x16x32_bf16(pa, vb, oacc[dt], 0, 0, 0);
      }
    }
    __builtin_amdgcn_s_setprio(0);

    __syncthreads();  // vmcnt(0): stage(t+1) landed (issued a full tile ago)
  }

  // normalize + store O bf16 [B,L,D]; inv broadcast like al
  float inv = 1.0f / lrow;
  f32x4 iv;
#pragma unroll
  for (int j = 0; j < 4; ++j) iv[j] = __shfl(inv, (lane & 48) | (lg * 4 + j));
  const int bg = bh / 12, h = bh % 12;
#pragma unroll
  for (int j = 0; j < 4; ++j) {
    int row = qr + lg * 4 + j;
#pragma unroll
    for (int dt = 0; dt < 4; ++dt) {
      gO[(size_t)(bg * 1024 + row) * 768 + h * 64 + dt * 16 + lr] =
          f2bf(oacc[dt][j] * iv[j]);
    }
  }
#undef STAGE
}

// ---------------- GEMM2: out = O @ w_out^T + b_out (fp32 out), 64x64 tiles --
__global__ __launch_bounds__(256) void k_gemm_out(
    const u16* __restrict__ Ob, const u16* __restrict__ Wb,
    const float* __restrict__ b_out, float* __restrict__ out) {
  __shared__ u16 As[64 * 64];
  __shared__ u16 Bs[64 * 64];
  const int tid = threadIdx.x;
  const int lane = tid & 63;
  const int w = tid >> 6;
  const int wm = (w >> 1) * 32;
  const int wn = (w & 1) * 32;
  const int lr = lane & 15;
  const int lg = lane >> 4;
  const int m0 = blockIdx.x * 64;
  const int n0 = blockIdx.y * 64;

  f32x4 acc[2][2];
#pragma unroll
  for (int i = 0; i < 2; ++i)
#pragma unroll
    for (int j = 0; j < 2; ++j) acc[i][j] = (f32x4){0.f, 0.f, 0.f, 0.f};

  for (int kt = 0; kt < 12; ++kt) {
    __syncthreads();
#pragma unroll
    for (int i = 0; i < 2; ++i) {
      int seg = i * 256 + tid;
      int row = seg >> 3;
      int sl = (seg & 7) ^ (row & 7);
      gll16(Ob + (size_t)(m0 + row) * 768 + kt * 64 + sl * 8, (char*)As + seg * 16);
      gll16(Wb + (size_t)(n0 + row) * 768 + kt * 64 + sl * 8, (char*)Bs + seg * 16);
    }
    __syncthreads();
#pragma unroll
    for (int kh = 0; kh < 2; ++kh) {
      bf16x8 af[2], bfr[2];
#pragma unroll
      for (int t = 0; t < 2; ++t) {
        int ra = wm + t * 16 + lr;
        af[t] = *(const bf16x8*)((const char*)As + ra * 128 +
                                 ((kh * 64 + lg * 16) ^ ((ra & 7) << 4)));
        int rb = wn + t * 16 + lr;
        bfr[t] = *(const bf16x8*)((const char*)Bs + rb * 128 +
                                  ((kh * 64 + lg * 16) ^ ((rb & 7) << 4)));
      }
#pragma unroll
      for (int mi = 0; mi < 2; ++mi)
#pragma unroll
        for (int ni = 0; ni < 2; ++ni)
          acc[mi][ni] = __builtin_amdgcn_mfma_f32_16x16x32_bf16(
              af[mi], bfr[ni], acc[mi][ni], 0, 0, 0);
    }
  }
#pragma unroll
  for (int ni = 0; ni < 2; ++ni) {
    int n = n0 + wn + ni * 16 + lr;
    float bias = b_out[n];
#pragma unroll
    for (int mi = 0; mi < 2; ++mi) {
#pragma unroll
      for (int j = 0; j < 4; ++j) {
        int m = m0 + wm + mi * 16 + lg * 4 + j;
        out[(size_t)m * 768 + n] = acc[mi][ni][j] + bias;
      }
    }
  }
}

extern "C" void kernel_launch(void* const* d_in, const int* in_sizes, int n_in,
                              void* d_out, int out_size, void* d_ws, size_t ws_size,
                              hipStream_t stream) {
  const float* x = (const float*)d_in[0];
  const float* attn_bias = (const float*)d_in[1];
  const float* w_in = (const float*)d_in[2];
  const float* b_in = (const float*)d_in[3];
  const float* w_out = (const float*)d_in[4];
  const float* b_out = (const float*)d_in[5];
  float* out = (float*)d_out;

  char* ws = (char*)d_ws;
  size_t off = 0;
  u16* xb = (u16*)(ws + off);  off += (size_t)M_ * D_ * 2;
  u16* wib = (u16*)(ws + off); off += (size_t)N3_ * D_ * 2;
  u16* wob = (u16*)(ws + off); off += (size_t)D_ * D_ * 2;
  u16* q = (u16*)(ws + off);   off += (size_t)48 * 1024 * 64 * 2;
  u16* k = (u16*)(ws + off);   off += (size_t)48 * 1024 * 64 * 2;
  u16* v = (u16*)(ws + off);   off += (size_t)48 * 1024 * 64 * 2;
  u16* vt = (u16*)(ws + off);  off += (size_t)48 * 1024 * 64 * 2;
  u16* ob = (u16*)(ws + off);  off += (size_t)M_ * D_ * 2;

  const int na4 = (M_ * D_) / 4;
  const int nb4 = (N3_ * D_) / 4;
  const int nc4 = (D_ * D_) / 4;
  k_cvt3<<<(na4 + nb4 + nc4 + 255) / 256, 256, 0, stream>>>(
      x, xb, na4, w_in, wib, nb4, w_out, wob, nc4);
  k_gemm_qkv<<<dim3(32, 18), 256, 0, stream>>>(xb, wib, b_in, q, k, v);
  k_transpose<<<768, 256, 0, stream>>>(v, vt);
  k_attn<<<768, 256, 0, stream>>>(q, k, vt, attn_bias, ob);
  k_gemm_out<<<dim3(64, 12), 256, 0, stream>>>(ob, wob, b_out, out);
}